// Round 9
// baseline (132.753 us; speedup 1.0000x reference)
//
#include <hip/hip_runtime.h>

// B=8, T=2048, C=768, H=64. x fp32 [B,T,C]; Wq/Wk/Wv fp32 [C,H]; out fp32 [B,T,H].
// R9: attn K/V traffic cut 8x — block = 128 q-rows (8 waves), K/V s-tile staged
//     into double-buffered LDS (global_load_lds) shared by all waves; prefetch
//     issued before compute so the barrier drain overlaps. qkv/wt/finalize = R8.

typedef __bf16 bf16x8 __attribute__((ext_vector_type(8)));
typedef float  f32x4  __attribute__((ext_vector_type(4)));
typedef unsigned int u32;

union ABu {
    bf16x8 v;
    uint4  u;
    unsigned short us[8];
};

__device__ __forceinline__ unsigned short f2bf(float f) {
    union { float f; unsigned int u; } c; c.f = f;
    unsigned int u = c.u + 0x7fffu + ((c.u >> 16) & 1u);   // RNE
    return (unsigned short)(u >> 16);
}

// async global->LDS, 16B per lane; dst must be wave-uniform base + lane*16
__device__ __forceinline__ void gld16(void* lds, const void* g) {
    __builtin_amdgcn_global_load_lds(
        (const u32 __attribute__((address_space(1)))*)g,
        (u32 __attribute__((address_space(3)))*)lds, 16, 0, 0);
}

// ---------------------------------------------------------------------------
// Kernel 1: W [768][64] fp32 -> wF fragment-major bf16.
// ---------------------------------------------------------------------------
__global__ __launch_bounds__(256)
void wt_kernel(const float* __restrict__ Wq, const float* __restrict__ Wk,
               const float* __restrict__ Wv, unsigned short* __restrict__ wF) {
    const int j   = blockIdx.x / 6;
    const int kgg = blockIdx.x % 6;
    const int t = threadIdx.x;
    const int kg = kgg * 4 + (t >> 6);
    const int lane = t & 63, quad = lane >> 4, l16 = lane & 15;
    const int m = j >> 2, nb = (j & 3) * 16;
    const float* W = (m == 0) ? Wq : (m == 1) ? Wk : Wv;
    ABu o;
#pragma unroll
    for (int i = 0; i < 8; ++i)
        o.us[i] = f2bf(W[(kg * 32 + quad * 8 + i) * 64 + nb + l16]);
    *(uint4*)(wF + ((size_t)(j * 24 + kg) * 64 + lane) * 8) = o.u;
}

// ---------------------------------------------------------------------------
// Kernel 2: QKV GEMM. 512 blocks x 512 threads (8 waves = mh x nh). (= R8)
// ---------------------------------------------------------------------------
__global__ __launch_bounds__(512, 4)
void qkv_kernel(const float* __restrict__ x, const unsigned short* __restrict__ wF,
                unsigned short* __restrict__ qF, unsigned short* __restrict__ kF,
                unsigned short* __restrict__ vF) {
    __shared__ float          xs[32][68];
    __shared__ unsigned short wsW[24][64][8];
    __shared__ unsigned short Cst[2][12][16][17];
    const int tid  = threadIdx.x;
    const int lane = tid & 63, w = tid >> 6;
    const int l16  = lane & 15, quad = lane >> 4;
    const int mh   = w & 1, nh = w >> 1;
    const int m0   = blockIdx.x * 32;
    const int b    = m0 >> 11;

    f32x4 acc[3];
#pragma unroll
    for (int j = 0; j < 3; ++j) acc[j] = (f32x4){0.f, 0.f, 0.f, 0.f};

    const int xrow = tid >> 4, xc16 = tid & 15;

    for (int kk = 0; kk < 12; ++kk) {
        __syncthreads();
#pragma unroll
        for (int i = 0; i < 3; ++i) {
            const int c = w * 3 + i;
            const int j = c >> 1, kg2 = c & 1;
            gld16((char*)wsW + (size_t)c * 1024 + lane * 16,
                  (const char*)wF + ((size_t)(j * 24 + kk * 2 + kg2) * 64 + lane) * 16);
        }
        *(float4*)&xs[xrow][xc16 * 4] =
            *(const float4*)&x[(size_t)(m0 + xrow) * 768 + kk * 64 + xc16 * 4];
        __syncthreads();

#pragma unroll
        for (int kg2 = 0; kg2 < 2; ++kg2) {
            const float* xr = &xs[mh * 16 + l16][kg2 * 32 + quad * 8];
            float4 f0 = *(const float4*)xr;
            float4 f1 = *(const float4*)(xr + 4);
            ABu af;
            af.us[0] = f2bf(f0.x); af.us[1] = f2bf(f0.y);
            af.us[2] = f2bf(f0.z); af.us[3] = f2bf(f0.w);
            af.us[4] = f2bf(f1.x); af.us[5] = f2bf(f1.y);
            af.us[6] = f2bf(f1.z); af.us[7] = f2bf(f1.w);
#pragma unroll
            for (int jl = 0; jl < 3; ++jl) {
                const int j = nh * 3 + jl;
                ABu bf;
                bf.u = *(const uint4*)((char*)wsW + (size_t)(j * 2 + kg2) * 1024 + lane * 16);
                acc[jl] = __builtin_amdgcn_mfma_f32_16x16x32_bf16(af.v, bf.v, acc[jl], 0, 0, 0);
            }
        }
    }

    __syncthreads();
#pragma unroll
    for (int jl = 0; jl < 3; ++jl)
#pragma unroll
        for (int r = 0; r < 4; ++r)
            Cst[mh][nh * 3 + jl][quad * 4 + r][l16] = f2bf(acc[jl][r]);
    __syncthreads();

    const int g = tid >> 6, el = tid & 63;
    const int eq = el >> 4, e16 = el & 15;
    if (g < 4) {
        const int mhh = g >> 1, kg = g & 1;
        ABu oq, ok;
#pragma unroll
        for (int i = 0; i < 8; ++i) {
            const int h = kg * 32 + eq * 8 + i;
            oq.us[i] = Cst[mhh][h >> 4][e16][h & 15];
            ok.us[i] = Cst[mhh][4 + (h >> 4)][e16][h & 15];
        }
        const size_t tt = (size_t)b * 128 + ((m0 & 2047) >> 4) + mhh;
        *(uint4*)(qF + ((tt * 2 + kg) * 64 + el) * 8) = oq.u;
        *(uint4*)(kF + ((tt * 2 + kg) * 64 + el) * 8) = ok.u;
    } else {
        const int nt = g & 3;
        const int sv = (m0 & 2047) >> 6, kg = (m0 >> 5) & 1;
        ABu ov;
#pragma unroll
        for (int i = 0; i < 8; ++i) {
            const int loc = eq * 8 + i;
            ov.us[i] = Cst[loc >> 4][8 + nt][loc & 15][e16];
        }
        *(uint4*)(vF + ((((size_t)(b * 32 + sv) * 4 + nt) * 2 + kg) * 64 + el) * 8) = ov.u;
    }
}

// ---------------------------------------------------------------------------
// Kernel 3: flash attention. 512 blocks x 512 threads (8 waves).
// Block = (b, 128-row q-superblock, s-quarter). K/V s-tile (16 KB) staged into
// double-buffered LDS shared by all 8 waves; prefetch before compute. Fixed-max
// softmax; partial O/l to private buffers.
// ---------------------------------------------------------------------------
__global__ __launch_bounds__(512, 4)
void attn_kernel(const unsigned short* __restrict__ qF,
                 const unsigned short* __restrict__ kF,
                 const unsigned short* __restrict__ vF,
                 float* __restrict__ opart, float* __restrict__ lpart) {
    __shared__ unsigned short KS[2][8][64][8];   // 16 KB double-buffered K
    __shared__ unsigned short VS[2][8][64][8];   // 16 KB double-buffered V
    __shared__ unsigned short PT[8][64][20];     // 20 KB per-wave P transpose
    const int tid  = threadIdx.x;
    const int lane = tid & 63, w = tid >> 6;     // 8 waves
    const int l16  = lane & 15, quad = lane >> 4;
    const int idx  = blockIdx.x;
    const int b    = idx >> 6;
    const int rem  = idx & 63;
    const int jj   = rem >> 2, quarter = rem & 3;
    const int qsuper = (jj & 1) ? (15 - (jj >> 1)) : (jj >> 1);  // heavy/light interleave
    const int tt   = qsuper * 8 + w;             // this wave's 16-row q-tile
    const int tq0  = tt * 16;
    const int stmax = 2 * qsuper + 1;            // last s-tile for this superblock
    const float L2E = 1.44269504089f;
    const float MFIX = 16.0f;

    ABu aq[2];
#pragma unroll
    for (int kg = 0; kg < 2; ++kg)
        aq[kg].u = *(const uint4*)(qF + ((((size_t)b * 128 + tt) * 2 + kg) * 64 + lane) * 8);

    f32x4 acc[4];
#pragma unroll
    for (int nt = 0; nt < 4; ++nt) acc[nt] = (f32x4){0.f, 0.f, 0.f, 0.f};
    float lrow[4] = {0.f, 0.f, 0.f, 0.f};

    const size_t stgoff = (size_t)w * 1024 + lane * 16;   // this wave's staging chunk

    // prologue stage into buf 0
    if (quarter <= stmax) {
        const char* ksrc = (const char*)(kF + (size_t)(b * 128 + quarter * 4) * 1024);
        const char* vsrc = (const char*)(vF + (size_t)(b * 32 + quarter) * 4096);
        gld16((char*)KS + stgoff, ksrc + stgoff);
        gld16((char*)VS + stgoff, vsrc + stgoff);
    }
    __syncthreads();

    int cur = 0;
    for (int st = quarter; st <= stmax; st += 4) {
        // prefetch next tile into the other buffer BEFORE computing this one
        const int nxt = st + 4;
        if (nxt <= stmax) {
            const char* ksrc = (const char*)(kF + (size_t)(b * 128 + nxt * 4) * 1024);
            const char* vsrc = (const char*)(vF + (size_t)(b * 32 + nxt) * 4096);
            gld16((char*)KS + (size_t)(cur ^ 1) * 8192 + stgoff, ksrc + stgoff);
            gld16((char*)VS + (size_t)(cur ^ 1) * 8192 + stgoff, vsrc + stgoff);
        }
        const int s0 = st * 64;
        if (s0 <= tq0 + 15) {    // wave-uniform causal skip (fully-masked tiles)
            float p[4][4];
#pragma unroll
            for (int nt = 0; nt < 4; ++nt) {
                ABu k0, k1;
                k0.u = *(const uint4*)((char*)KS + (size_t)cur * 8192 + (nt * 2 + 0) * 1024 + lane * 16);
                k1.u = *(const uint4*)((char*)KS + (size_t)cur * 8192 + (nt * 2 + 1) * 1024 + lane * 16);
                f32x4 s = (f32x4){0.f, 0.f, 0.f, 0.f};
                s = __builtin_amdgcn_mfma_f32_16x16x32_bf16(aq[0].v, k0.v, s, 0, 0, 0);
                s = __builtin_amdgcn_mfma_f32_16x16x32_bf16(aq[1].v, k1.v, s, 0, 0, 0);
                const int sg = s0 + nt * 16 + l16;
#pragma unroll
                for (int r = 0; r < 4; ++r) {
                    float sc = (sg > tq0 + quad * 4 + r) ? -1e30f : s[r] * 0.125f;
                    float pv = exp2f((sc - MFIX) * L2E);
                    p[nt][r] = pv;
                    lrow[r] += pv;
                }
            }
            // P: C-layout -> wave-private LDS transpose -> A-layout fragments
#pragma unroll
            for (int nt = 0; nt < 4; ++nt) {
                ushort4 pw;
                pw.x = f2bf(p[nt][0]); pw.y = f2bf(p[nt][1]);
                pw.z = f2bf(p[nt][2]); pw.w = f2bf(p[nt][3]);
                *(ushort4*)&PT[w][nt * 16 + l16][quad * 4] = pw;
            }
            ABu ap[2];
#pragma unroll
            for (int ks = 0; ks < 2; ++ks)
#pragma unroll
                for (int j = 0; j < 8; ++j)
                    ap[ks].us[j] = PT[w][ks * 32 + quad * 8 + j][l16];
#pragma unroll
            for (int nt = 0; nt < 4; ++nt) {
                ABu v0, v1;
                v0.u = *(const uint4*)((char*)VS + (size_t)cur * 8192 + (nt * 2 + 0) * 1024 + lane * 16);
                v1.u = *(const uint4*)((char*)VS + (size_t)cur * 8192 + (nt * 2 + 1) * 1024 + lane * 16);
                acc[nt] = __builtin_amdgcn_mfma_f32_16x16x32_bf16(ap[0].v, v0.v, acc[nt], 0, 0, 0);
                acc[nt] = __builtin_amdgcn_mfma_f32_16x16x32_bf16(ap[1].v, v1.v, acc[nt], 0, 0, 0);
            }
        }
        __syncthreads();   // buf(cur) reads done; prefetch(cur^1) drained
        cur ^= 1;
    }

    // ---- epilogue: plain stores to private partial buffers (always runs) ----
#pragma unroll
    for (int off = 1; off <= 8; off <<= 1)
#pragma unroll
        for (int r = 0; r < 4; ++r)
            lrow[r] += __shfl_xor(lrow[r], off);

    float* obase = opart + ((size_t)(quarter * 8 + b) * 2048 + tq0) * 64;
#pragma unroll
    for (int nt = 0; nt < 4; ++nt)
#pragma unroll
        for (int r = 0; r < 4; ++r)
            obase[(size_t)(quad * 4 + r) * 64 + nt * 16 + l16] = acc[nt][r];
    if (l16 == 0) {
#pragma unroll
        for (int r = 0; r < 4; ++r)
            lpart[(size_t)(quarter * 8 + b) * 2048 + tq0 + quad * 4 + r] = lrow[r];
    }
}

// ---------------------------------------------------------------------------
// Kernel 4: finalize — out = (sum of 4 partial O) / (sum of 4 partial l).
// ---------------------------------------------------------------------------
__global__ __launch_bounds__(256)
void finalize_kernel(const float* __restrict__ opart, const float* __restrict__ lpart,
                     float* __restrict__ out) {
    const int idx = blockIdx.x * 256 + threadIdx.x;
    const int row = idx >> 4;
    float4 v = ((const float4*)opart)[idx];
    float  l = lpart[row];
#pragma unroll
    for (int q = 1; q < 4; ++q) {
        float4 u = ((const float4*)opart)[(size_t)q * 262144 + idx];
        v.x += u.x; v.y += u.y; v.z += u.z; v.w += u.w;
        l += lpart[(size_t)q * 16384 + row];
    }
    const float li = 1.f / l;
    v.x *= li; v.y *= li; v.z *= li; v.w *= li;
    ((float4*)out)[idx] = v;
}

// ---------------------------------------------------------------------------
extern "C" void kernel_launch(void* const* d_in, const int* in_sizes, int n_in,
                              void* d_out, int out_size, void* d_ws, size_t ws_size,
                              hipStream_t stream) {
    const float* x  = (const float*)d_in[0];
    const float* Wq = (const float*)d_in[1];
    const float* Wk = (const float*)d_in[2];
    const float* Wv = (const float*)d_in[3];
    float* out = (float*)d_out;

    char* ws = (char*)d_ws;
    unsigned short* wF    = (unsigned short*)ws;                              // 288 KB
    unsigned short* qF    = (unsigned short*)(ws + (512 << 10));              // 2 MB
    unsigned short* kF    = (unsigned short*)(ws + (512 << 10) + (2 << 20));  // 2 MB
    unsigned short* vF    = (unsigned short*)(ws + (512 << 10) + (4 << 20));  // 2 MB
    float*          opart = (float*)(ws + (512 << 10) + (6 << 20));           // 16 MB
    float*          lpart = (float*)(ws + (512 << 10) + (22 << 20));          // 256 KB

    wt_kernel<<<72, 256, 0, stream>>>(Wq, Wk, Wv, wF);
    qkv_kernel<<<512, 512, 0, stream>>>(x, wF, qF, kF, vF);
    attn_kernel<<<512, 512, 0, stream>>>(qF, kF, vF, opart, lpart);
    finalize_kernel<<<1024, 256, 0, stream>>>(opart, lpart, out);
}

// Round 10
// 128.053 us; speedup vs baseline: 1.0367x; 1.0367x over previous
//
#include <hip/hip_runtime.h>

// B=8, T=2048, C=768, H=64. x fp32 [B,T,C]; Wq/Wk/Wv fp32 [C,H]; out fp32 [B,T,H].
// R10 consolidation: qkv double-buffered (1 barrier/iter, prefetch overlapped),
//     attn = R8 direct-load barrier-free body with bf16 partial-O, finalize bf16.

typedef __bf16 bf16x8 __attribute__((ext_vector_type(8)));
typedef float  f32x4  __attribute__((ext_vector_type(4)));
typedef unsigned int u32;

union ABu {
    bf16x8 v;
    uint4  u;
    unsigned short us[8];
};

__device__ __forceinline__ unsigned short f2bf(float f) {
    union { float f; unsigned int u; } c; c.f = f;
    unsigned int u = c.u + 0x7fffu + ((c.u >> 16) & 1u);   // RNE
    return (unsigned short)(u >> 16);
}
__device__ __forceinline__ float bf2f(unsigned short s) {
    union { unsigned int u; float f; } c; c.u = ((unsigned int)s) << 16;
    return c.f;
}

// async global->LDS, 16B per lane; dst must be wave-uniform base + lane*16
__device__ __forceinline__ void gld16(void* lds, const void* g) {
    __builtin_amdgcn_global_load_lds(
        (const u32 __attribute__((address_space(1)))*)g,
        (u32 __attribute__((address_space(3)))*)lds, 16, 0, 0);
}

// ---------------------------------------------------------------------------
// Kernel 1: W [768][64] fp32 -> wF fragment-major bf16.
// ---------------------------------------------------------------------------
__global__ __launch_bounds__(256)
void wt_kernel(const float* __restrict__ Wq, const float* __restrict__ Wk,
               const float* __restrict__ Wv, unsigned short* __restrict__ wF) {
    const int j   = blockIdx.x / 6;
    const int kgg = blockIdx.x % 6;
    const int t = threadIdx.x;
    const int kg = kgg * 4 + (t >> 6);
    const int lane = t & 63, quad = lane >> 4, l16 = lane & 15;
    const int m = j >> 2, nb = (j & 3) * 16;
    const float* W = (m == 0) ? Wq : (m == 1) ? Wk : Wv;
    ABu o;
#pragma unroll
    for (int i = 0; i < 8; ++i)
        o.us[i] = f2bf(W[(kg * 32 + quad * 8 + i) * 64 + nb + l16]);
    *(uint4*)(wF + ((size_t)(j * 24 + kg) * 64 + lane) * 8) = o.u;
}

// ---------------------------------------------------------------------------
// Kernel 2: QKV GEMM, double-buffered. 512 blocks x 512 threads (8 waves).
// One barrier per k-iteration; next W slice (global_load_lds) + x tile
// prefetched during compute. LDS 78.5 KB -> 2 blocks/CU.
// ---------------------------------------------------------------------------
__global__ __launch_bounds__(512, 4)
void qkv_kernel(const float* __restrict__ x, const unsigned short* __restrict__ wF,
                unsigned short* __restrict__ qF, unsigned short* __restrict__ kF,
                unsigned short* __restrict__ vF) {
    __shared__ float          xs[2][32][68];          // 17.4 KB
    __shared__ unsigned short wsW[2][24][64][8];      // 48 KB
    __shared__ unsigned short Cst[2][12][16][17];     // 13.1 KB
    const int tid  = threadIdx.x;
    const int lane = tid & 63, w = tid >> 6;
    const int l16  = lane & 15, quad = lane >> 4;
    const int mh   = w & 1, nh = w >> 1;
    const int m0   = blockIdx.x * 32;
    const int b    = m0 >> 11;

    f32x4 acc[3];
#pragma unroll
    for (int j = 0; j < 3; ++j) acc[j] = (f32x4){0.f, 0.f, 0.f, 0.f};

    const int xrow = tid >> 4, xc16 = tid & 15;       // 512 thr = 32 rows x 16 float4

    // prologue: stage iter 0 into buffer 0
#pragma unroll
    for (int i = 0; i < 3; ++i) {
        const int c = w * 3 + i, j = c >> 1, kg2 = c & 1;
        gld16((char*)wsW[0] + (size_t)c * 1024 + lane * 16,
              (const char*)wF + ((size_t)(j * 24 + kg2) * 64 + lane) * 16);
    }
    *(float4*)&xs[0][xrow][xc16 * 4] =
        *(const float4*)&x[(size_t)(m0 + xrow) * 768 + xc16 * 4];
    __syncthreads();

    for (int kk = 0; kk < 12; ++kk) {
        const int cur = kk & 1, nxt = cur ^ 1;
        float4 xn;
        if (kk + 1 < 12) {
            // prefetch next W slice (async -> LDS) and next x tile (-> regs)
#pragma unroll
            for (int i = 0; i < 3; ++i) {
                const int c = w * 3 + i, j = c >> 1, kg2 = c & 1;
                gld16((char*)wsW[nxt] + (size_t)c * 1024 + lane * 16,
                      (const char*)wF + ((size_t)(j * 24 + (kk + 1) * 2 + kg2) * 64 + lane) * 16);
            }
            xn = *(const float4*)&x[(size_t)(m0 + xrow) * 768 + (kk + 1) * 64 + xc16 * 4];
        }

        // compute current buffer
#pragma unroll
        for (int kg2 = 0; kg2 < 2; ++kg2) {
            const float* xr = &xs[cur][mh * 16 + l16][kg2 * 32 + quad * 8];
            float4 f0 = *(const float4*)xr;
            float4 f1 = *(const float4*)(xr + 4);
            ABu af;
            af.us[0] = f2bf(f0.x); af.us[1] = f2bf(f0.y);
            af.us[2] = f2bf(f0.z); af.us[3] = f2bf(f0.w);
            af.us[4] = f2bf(f1.x); af.us[5] = f2bf(f1.y);
            af.us[6] = f2bf(f1.z); af.us[7] = f2bf(f1.w);
#pragma unroll
            for (int jl = 0; jl < 3; ++jl) {
                const int j = nh * 3 + jl;
                ABu bf;
                bf.u = *(const uint4*)((char*)wsW[cur] + (size_t)(j * 2 + kg2) * 1024 + lane * 16);
                acc[jl] = __builtin_amdgcn_mfma_f32_16x16x32_bf16(af.v, bf.v, acc[jl], 0, 0, 0);
            }
        }

        if (kk + 1 < 12)
            *(float4*)&xs[nxt][xrow][xc16 * 4] = xn;   // waitcnt lands here, post-compute
        __syncthreads();   // drains prefetch; protects cur for next overwrite
    }

    // ---- epilogue: C-frags -> Cst (bf16) -> fragment-major stores ----
#pragma unroll
    for (int jl = 0; jl < 3; ++jl)
#pragma unroll
        for (int r = 0; r < 4; ++r)
            Cst[mh][nh * 3 + jl][quad * 4 + r][l16] = f2bf(acc[jl][r]);
    __syncthreads();

    const int g = tid >> 6, el = tid & 63;
    const int eq = el >> 4, e16 = el & 15;
    if (g < 4) {   // Q and K frags
        const int mhh = g >> 1, kg = g & 1;
        ABu oq, ok;
#pragma unroll
        for (int i = 0; i < 8; ++i) {
            const int h = kg * 32 + eq * 8 + i;
            oq.us[i] = Cst[mhh][h >> 4][e16][h & 15];
            ok.us[i] = Cst[mhh][4 + (h >> 4)][e16][h & 15];
        }
        const size_t tt = (size_t)b * 128 + ((m0 & 2047) >> 4) + mhh;
        *(uint4*)(qF + ((tt * 2 + kg) * 64 + el) * 8) = oq.u;
        *(uint4*)(kF + ((tt * 2 + kg) * 64 + el) * 8) = ok.u;
    } else {       // V frags
        const int nt = g & 3;
        const int sv = (m0 & 2047) >> 6, kg = (m0 >> 5) & 1;
        ABu ov;
#pragma unroll
        for (int i = 0; i < 8; ++i) {
            const int loc = eq * 8 + i;
            ov.us[i] = Cst[loc >> 4][8 + nt][loc & 15][e16];
        }
        *(uint4*)(vF + ((((size_t)(b * 32 + sv) * 4 + nt) * 2 + kg) * 64 + el) * 8) = ov.u;
    }
}

// ---------------------------------------------------------------------------
// Kernel 3: flash attention, barrier-free (R8 body). 1024 blocks x 256 thr.
// Frag-major K/V loaded directly (coalesced 1KB/instr); fixed-max softmax;
// bf16 partial-O + fp32 partial-l to private buffers.
// ---------------------------------------------------------------------------
__global__ __launch_bounds__(256, 4)
void attn_kernel(const unsigned short* __restrict__ qF,
                 const unsigned short* __restrict__ kF,
                 const unsigned short* __restrict__ vF,
                 unsigned short* __restrict__ opart, float* __restrict__ lpart) {
    __shared__ unsigned short PT[4][64][20];
    const int tid  = threadIdx.x;
    const int lane = tid & 63, w = tid >> 6;
    const int l16  = lane & 15, quad = lane >> 4;
    const int idx  = blockIdx.x;
    const int b    = idx >> 7;
    const int rem  = idx & 127;
    const int jj   = rem >> 2, quarter = rem & 3;
    const int qs   = (jj & 1) ? (31 - (jj >> 1)) : (jj >> 1);   // heavy/light interleave
    const int tt   = qs * 4 + w;
    const int tq0  = tt * 16;
    const float L2E = 1.44269504089f;
    const float MFIX = 16.0f;

    ABu aq[2];
#pragma unroll
    for (int kg = 0; kg < 2; ++kg)
        aq[kg].u = *(const uint4*)(qF + ((((size_t)b * 128 + tt) * 2 + kg) * 64 + lane) * 8);

    f32x4 acc[4];
#pragma unroll
    for (int nt = 0; nt < 4; ++nt) acc[nt] = (f32x4){0.f, 0.f, 0.f, 0.f};
    float lrow[4] = {0.f, 0.f, 0.f, 0.f};

    for (int st = quarter; st <= qs; st += 4) {
        const int s0 = st * 64;
        const unsigned short* kbase = kF + (size_t)(b * 128 + st * 4) * 1024;
        const unsigned short* vbase = vF + (size_t)(b * 32 + st) * 4096;
        ABu kf[8];
#pragma unroll
        for (int c = 0; c < 8; ++c)
            kf[c].u = *(const uint4*)(kbase + (size_t)c * 512 + lane * 8);
        float p[4][4];
#pragma unroll
        for (int nt = 0; nt < 4; ++nt) {
            f32x4 s = (f32x4){0.f, 0.f, 0.f, 0.f};
            s = __builtin_amdgcn_mfma_f32_16x16x32_bf16(aq[0].v, kf[nt * 2 + 0].v, s, 0, 0, 0);
            s = __builtin_amdgcn_mfma_f32_16x16x32_bf16(aq[1].v, kf[nt * 2 + 1].v, s, 0, 0, 0);
            const int sg = s0 + nt * 16 + l16;
#pragma unroll
            for (int r = 0; r < 4; ++r) {
                float sc = (sg > tq0 + quad * 4 + r) ? -1e30f : s[r] * 0.125f;
                float pv = exp2f((sc - MFIX) * L2E);
                p[nt][r] = pv;
                lrow[r] += pv;
            }
        }
        ABu vf[8];
#pragma unroll
        for (int c = 0; c < 8; ++c)
            vf[c].u = *(const uint4*)(vbase + (size_t)c * 512 + lane * 8);
#pragma unroll
        for (int nt = 0; nt < 4; ++nt) {
            ushort4 pw;
            pw.x = f2bf(p[nt][0]); pw.y = f2bf(p[nt][1]);
            pw.z = f2bf(p[nt][2]); pw.w = f2bf(p[nt][3]);
            *(ushort4*)&PT[w][nt * 16 + l16][quad * 4] = pw;
        }
        ABu ap[2];
#pragma unroll
        for (int ks = 0; ks < 2; ++ks)
#pragma unroll
            for (int j = 0; j < 8; ++j)
                ap[ks].us[j] = PT[w][ks * 32 + quad * 8 + j][l16];
#pragma unroll
        for (int nt = 0; nt < 4; ++nt) {
            acc[nt] = __builtin_amdgcn_mfma_f32_16x16x32_bf16(ap[0].v, vf[nt * 2 + 0].v, acc[nt], 0, 0, 0);
            acc[nt] = __builtin_amdgcn_mfma_f32_16x16x32_bf16(ap[1].v, vf[nt * 2 + 1].v, acc[nt], 0, 0, 0);
        }
    }

    // ---- epilogue: bf16 partial-O, fp32 partial-l ----
#pragma unroll
    for (int off = 1; off <= 8; off <<= 1)
#pragma unroll
        for (int r = 0; r < 4; ++r)
            lrow[r] += __shfl_xor(lrow[r], off);

    unsigned short* obase = opart + ((size_t)(quarter * 8 + b) * 2048 + tq0) * 64;
#pragma unroll
    for (int nt = 0; nt < 4; ++nt)
#pragma unroll
        for (int r = 0; r < 4; ++r)
            obase[(size_t)(quad * 4 + r) * 64 + nt * 16 + l16] = f2bf(acc[nt][r]);
    if (l16 == 0) {
#pragma unroll
        for (int r = 0; r < 4; ++r)
            lpart[(size_t)(quarter * 8 + b) * 2048 + tq0 + quad * 4 + r] = lrow[r];
    }
}

// ---------------------------------------------------------------------------
// Kernel 4: finalize — out = (sum of 4 bf16 partial O) / (sum of 4 partial l).
// ---------------------------------------------------------------------------
__global__ __launch_bounds__(256)
void finalize_kernel(const unsigned short* __restrict__ opart,
                     const float* __restrict__ lpart, float* __restrict__ out) {
    const int idx = blockIdx.x * 256 + threadIdx.x;     // 4-elem group, 262144 total
    const int row = idx >> 4;
    float4 v = (float4){0.f, 0.f, 0.f, 0.f};
    float  l = 0.f;
#pragma unroll
    for (int q = 0; q < 4; ++q) {
        ushort4 u = ((const ushort4*)opart)[(size_t)q * 262144 + idx];
        v.x += bf2f(u.x); v.y += bf2f(u.y); v.z += bf2f(u.z); v.w += bf2f(u.w);
        l += lpart[(size_t)q * 16384 + row];
    }
    const float li = 1.f / l;
    v.x *= li; v.y *= li; v.z *= li; v.w *= li;
    ((float4*)out)[idx] = v;
}

// ---------------------------------------------------------------------------
extern "C" void kernel_launch(void* const* d_in, const int* in_sizes, int n_in,
                              void* d_out, int out_size, void* d_ws, size_t ws_size,
                              hipStream_t stream) {
    const float* x  = (const float*)d_in[0];
    const float* Wq = (const float*)d_in[1];
    const float* Wk = (const float*)d_in[2];
    const float* Wv = (const float*)d_in[3];
    float* out = (float*)d_out;

    char* ws = (char*)d_ws;
    unsigned short* wF    = (unsigned short*)ws;                              // 288 KB
    unsigned short* qF    = (unsigned short*)(ws + (512 << 10));              // 2 MB
    unsigned short* kF    = (unsigned short*)(ws + (512 << 10) + (2 << 20));  // 2 MB
    unsigned short* vF    = (unsigned short*)(ws + (512 << 10) + (4 << 20));  // 2 MB
    unsigned short* opart = (unsigned short*)(ws + (512 << 10) + (6 << 20));  // 8 MB bf16
    float*          lpart = (float*)(ws + (512 << 10) + (14 << 20));          // 256 KB

    wt_kernel<<<72, 256, 0, stream>>>(Wq, Wk, Wv, wF);
    qkv_kernel<<<512, 512, 0, stream>>>(x, wF, qF, kF, vF);
    attn_kernel<<<1024, 256, 0, stream>>>(qF, kF, vF, opart, lpart);
    finalize_kernel<<<1024, 256, 0, stream>>>(opart, lpart, out);
}